// Round 1
// baseline (300.969 us; speedup 1.0000x reference)
//
#include <hip/hip_runtime.h>
#include <hip/hip_bf16.h>

typedef _Float16 f16;
typedef _Float16 half8 __attribute__((ext_vector_type(8)));
typedef _Float16 half4 __attribute__((ext_vector_type(4)));
typedef float f32x4 __attribute__((ext_vector_type(4)));
typedef unsigned short u16;
typedef unsigned int u32;

#define AS_GLOBAL __attribute__((address_space(1)))
#define AS_LDS    __attribute__((address_space(3)))

static __device__ __forceinline__ f32x4 mfma_k32(half8 a, half8 b, f32x4 c) {
  return __builtin_amdgcn_mfma_f32_16x16x32_f16(a, b, c, 0, 0, 0);
}

// async global->LDS, 16B per lane; LDS dest is wave-uniform base, HW adds lane*16
static __device__ __forceinline__ void glds16(const void* g, void* l) {
  __builtin_amdgcn_global_load_lds((const AS_GLOBAL u32*)(unsigned long long)g,
                                   (AS_LDS u32*)l, 16, 0, 0);
}

// ---------------- f32 -> f16 convert (8 elems/thread) ----------------
__global__ __launch_bounds__(256) void cvt_kernel(const float* __restrict__ src,
                                                  f16* __restrict__ dst, int n) {
  long i = ((long)blockIdx.x * 256 + threadIdx.x) * 8;
  if (i + 8 <= n) {
    const float4 a = *(const float4*)(src + i);
    const float4 b = *(const float4*)(src + i + 4);
    union { uint4 v; f16 h[8]; } o;
    o.h[0] = (f16)a.x; o.h[1] = (f16)a.y; o.h[2] = (f16)a.z; o.h[3] = (f16)a.w;
    o.h[4] = (f16)b.x; o.h[5] = (f16)b.y; o.h[6] = (f16)b.z; o.h[7] = (f16)b.w;
    *(uint4*)(dst + i) = o.v;
  }
}

// ---------------- shared 128x128 GEMM core: C = A(MxK) * B(NxK)^T ----------------
// m97 pattern: BK=32, unpadded LDS, global_load_lds width=16; wave w stages
// rows [32w,32w+32) of both tiles; LDS offset == lane*16B within each 16-row chunk.
static __device__ __forceinline__ void gemm128(const f16* __restrict__ A, const f16* __restrict__ B,
                                               const int K, const long m0, const long n0,
                                               f16* As, f16* Bs, f32x4 acc[4][4]) {
  const int tid = threadIdx.x;
  const int lane = tid & 63, w = tid >> 6;
  const int l15 = lane & 15, qd = lane >> 4;
  const int wr = w >> 1, wc = w & 1;
  const int rs   = lane >> 2;        // staging row within 16-row chunk
  const int kofs = (lane & 3) * 8;   // staging k offset (8 f16 = 16B)
  const f16* gA0 = A + (m0 + 32 * w + rs) * (long)K + kofs;
  const f16* gA1 = gA0 + 16 * (long)K;
  const f16* gB0 = B + (n0 + 32 * w + rs) * (long)K + kofs;
  const f16* gB1 = gB0 + 16 * (long)K;
  f16* lA0 = As + (32 * w) * 32;  f16* lA1 = lA0 + 512;
  f16* lB0 = Bs + (32 * w) * 32;  f16* lB1 = lB0 + 512;
  const int nIter = K >> 5;
  for (int kt = 0; kt < nIter; ++kt) {
    const int ko = kt * 32;
    glds16(gA0 + ko, lA0);
    glds16(gA1 + ko, lA1);
    glds16(gB0 + ko, lB0);
    glds16(gB1 + ko, lB1);
    __syncthreads();
    half8 a[4], b[4];
#pragma unroll
    for (int i = 0; i < 4; ++i)
      a[i] = *(const half8*)(As + (64 * wr + 16 * i + l15) * 32 + qd * 8);
#pragma unroll
    for (int j = 0; j < 4; ++j)
      b[j] = *(const half8*)(Bs + (64 * wc + 16 * j + l15) * 32 + qd * 8);
#pragma unroll
    for (int i = 0; i < 4; ++i)
#pragma unroll
      for (int j = 0; j < 4; ++j)
        acc[i][j] = mfma_k32(a[i], b[j], acc[i][j]);
    __syncthreads();
  }
}

// ---------------- QKV GEMM + fused bias + 2D-RoPE + scatter into (B,H,N,64) ----------------
// RoPE in epilogue: element (n, d) pairs with (n, d^1) held by lane^1 (same quad).
// Wave-uniform `which` branch; Q also gets 0.125*log2(e) folded in.
__global__ __launch_bounds__(256) void qkv_kernel(const f16* __restrict__ X, const f16* __restrict__ W,
                                                  const float* __restrict__ bias,
                                                  f16* __restrict__ Qf, f16* __restrict__ Kf,
                                                  f16* __restrict__ Vf) {
  __shared__ __align__(16) f16 As[4096];
  __shared__ __align__(16) f16 Bs[4096];
  f32x4 acc[4][4];
#pragma unroll
  for (int i = 0; i < 4; ++i)
#pragma unroll
    for (int j = 0; j < 4; ++j) acc[i][j] = (f32x4){0.f, 0.f, 0.f, 0.f};
  const long m0 = (long)blockIdx.x * 128;
  const long n0 = (long)blockIdx.y * 128;
  gemm128(X, W, 768, m0, n0, As, Bs, acc);

  const int tid = threadIdx.x, lane = tid & 63, w = tid >> 6;
  const int l15 = lane & 15, qd = lane >> 4;
  const int wr = w >> 1, wc = w & 1;
  const int bb = (int)(m0 >> 10);               // batch (uniform per block)
  const int slot = (int)(n0 >> 6) + wc;         // 0..35 (uniform per wave)
  const int which = slot / 12, h = slot % 12;
  f16* dst0 = (which == 0) ? Qf : (which == 1) ? Kf : Vf;
  f16* dstbh = dst0 + ((long)(bb * 12 + h)) * 1024 * 64;
  const bool doRope = (which != 2);
  const bool isQ = (which == 0);
  const bool odd = (l15 & 1);
#pragma unroll
  for (int j = 0; j < 4; ++j) {
    const int d = 16 * j + l15;
    const int p = d >> 1;                        // pair index 0..31
    const float fr = exp2f(-0.8304820237218405f * (float)(p & 15)); // 10000^(-(p%16)/16)
    const bool useY = (p < 16);                  // uniform per j (j<2)
    const float bv = bias[n0 + 64 * wc + d];
#pragma unroll
    for (int i = 0; i < 4; ++i) {
      const int nbase = (int)(m0 & 1023) + 64 * wr + 16 * i + qd * 4;
#pragma unroll
      for (int r = 0; r < 4; ++r) {
        const int n = nbase + r;
        float v = acc[i][j][r] + bv;
        if (doRope) {
          const float pv = __shfl_xor(v, 1, 64);   // partner element (d^1)
          const float pos = useY ? (float)(n >> 5) : (float)(n & 31);
          float sn, cn;
          __sincosf(pos * fr, &sn, &cn);
          // even d: r1 = t1*c - t2*s ; odd d: r2 = t1*s + t2*c  (t1=even elem, t2=odd elem)
          float res = odd ? (pv * sn + v * cn) : (v * cn - pv * sn);
          if (isQ) res *= 0.18033688011112042f;    // attn scale * log2(e)
          v = res;
        }
        dstbh[(long)n * 64 + d] = (f16)v;
      }
    }
  }
}

// ---------------- flash attention: block = (qtile of 128 rows, bh), 4 waves ----------------
// S^T register trick: compute K.Q^T (A=K, B=Q) so the 16x16 C-layout holds
// S^T with query=lane&15, key=qd*4+r. PV now also runs at the full x32 rate:
// MFMA contracts A,B positionally over k=qd*8+j, so applying the SAME
// key-permutation to the P fragment (lane keeps its own keys) and the V^T
// fragment (read at those keys) is exact — no cross-lane repack needed.
// T14: next tile's global loads issue right after the first barrier so their
// latency hides under QK^T/PV. XCD swizzle keeps each bh's K/V in one L2.
__global__ __launch_bounds__(256) void attn_kernel(const f16* __restrict__ Qf, const f16* __restrict__ Kf,
                                                   const f16* __restrict__ Vf, f16* __restrict__ Aout) {
  // Round-robin dispatch: linear id % 8 -> XCD. Give each XCD 24 contiguous bh
  // (all 8 q-tiles of a bh on one XCD) so the 256 KB K/V panel stays L2-resident.
  const int lin = (int)blockIdx.x + ((int)blockIdx.y << 3);   // 0..1535
  const int xcd = lin & 7, idx = lin >> 3;                    // idx 0..191
  const int bh = xcd * 24 + (idx >> 3);                       // bijective remap
  const int qt = idx & 7;
  const int b = bh / 12, h = bh % 12;
  const int tid = threadIdx.x;
  const int lane = tid & 63, w = tid >> 6;
  const int l15 = lane & 15, qd = lane >> 4;

  __shared__ __align__(16) f16 Ks[64][72];   // [key][d], rows padded to 72
  __shared__ __align__(16) f16 Vts[64][72];  // [d][key] (transposed)
  __shared__ float wsum[128];

  const f16* Qg = Qf + ((long)bh * 1024 + qt * 128) * 64;
  const f16* Kg = Kf + (long)bh * 1024 * 64;
  const f16* Vg = Vf + (long)bh * 1024 * 64;

  // Q register-resident: B-operand of x32 MFMA: B[k=qd*8+j][n=l15]
  half8 qb[2][2];
#pragma unroll
  for (int g = 0; g < 2; ++g)
#pragma unroll
    for (int dc = 0; dc < 2; ++dc)
      qb[g][dc] = *(const half8*)(Qg + (w * 32 + g * 16 + l15) * 64 + dc * 32 + qd * 8);

  float lsum[2] = {0.f, 0.f};
  f32x4 O[2][4];
#pragma unroll
  for (int g = 0; g < 2; ++g)
#pragma unroll
    for (int nt = 0; nt < 4; ++nt) O[g][nt] = (f32x4){0.f, 0.f, 0.f, 0.f};

  // staging addresses (per-thread, constant across kt)
  const int srow = tid >> 2, sch = (tid & 3) * 16;
  const f16* kgb = Kg + (long)srow * 64 + sch;
  const int sk0 = (tid & 31) * 2, scd = tid >> 5;
  const f16* vgb = Vg + (long)sk0 * 64 + scd * 8;
  uint4 kr0, kr1, vr0, vr1;

  // prologue: load tile 0 into registers
  kr0 = *(const uint4*)(kgb);
  kr1 = *(const uint4*)(kgb + 8);
  vr0 = *(const uint4*)(vgb);
  vr1 = *(const uint4*)(vgb + 64);

  for (int kt = 0; kt < 16; ++kt) {
    // write the staged tile to LDS (compiler inserts the vmcnt wait)
    *(uint4*)(&Ks[srow][sch])     = kr0;
    *(uint4*)(&Ks[srow][sch + 8]) = kr1;
    {
      union { uint4 u; f16 hh[8]; } ua, ub;
      ua.u = vr0; ub.u = vr1;
#pragma unroll
      for (int i2 = 0; i2 < 8; ++i2) {
        union { u32 u; f16 hh[2]; } t2;
        t2.hh[0] = ua.hh[i2]; t2.hh[1] = ub.hh[i2];
        *(u32*)(&Vts[scd * 8 + i2][sk0]) = t2.u;
      }
    }
    __syncthreads();

    // T14: issue NEXT tile's global loads now; latency hides under compute
    if (kt < 15) {
      const f16* kp = kgb + (kt + 1) * 4096;
      kr0 = *(const uint4*)(kp);
      kr1 = *(const uint4*)(kp + 8);
      const f16* vp = vgb + (kt + 1) * 4096;
      vr0 = *(const uint4*)(vp);
      vr1 = *(const uint4*)(vp + 64);
    }

    // S^T = K . Q^T  (x32 MFMAs; A=K from LDS, B=Q regs)
    f32x4 S[2][4];
#pragma unroll
    for (int kb = 0; kb < 4; ++kb) {
      const half8 ka0 = *(const half8*)(&Ks[kb * 16 + l15][qd * 8]);
      const half8 ka1 = *(const half8*)(&Ks[kb * 16 + l15][32 + qd * 8]);
#pragma unroll
      for (int g = 0; g < 2; ++g) {
        f32x4 z = (f32x4){0.f, 0.f, 0.f, 0.f};
        z = mfma_k32(ka0, qb[g][0], z);
        z = mfma_k32(ka1, qb[g][1], z);
        S[g][kb] = z;
      }
    }

    // P = exp2(S^T) packed straight into x32 PV A-fragments (no cross-lane:
    // lane's A positions qd*8+j hold its own keys {32c+4qd+r, 32c+16+4qd+r})
    half8 pa8[2][2];
#pragma unroll
    for (int g = 0; g < 2; ++g)
#pragma unroll
      for (int c = 0; c < 2; ++c) {
        const f32x4 s0 = S[g][2 * c], s1 = S[g][2 * c + 1];
        const float p0 = __builtin_amdgcn_exp2f(s0[0]);
        const float p1 = __builtin_amdgcn_exp2f(s0[1]);
        const float p2 = __builtin_amdgcn_exp2f(s0[2]);
        const float p3 = __builtin_amdgcn_exp2f(s0[3]);
        const float p4 = __builtin_amdgcn_exp2f(s1[0]);
        const float p5 = __builtin_amdgcn_exp2f(s1[1]);
        const float p6 = __builtin_amdgcn_exp2f(s1[2]);
        const float p7 = __builtin_amdgcn_exp2f(s1[3]);
        lsum[g] += ((p0 + p1) + (p2 + p3)) + ((p4 + p5) + (p6 + p7));
        half8 pk;
        pk[0] = (f16)p0; pk[1] = (f16)p1; pk[2] = (f16)p2; pk[3] = (f16)p3;
        pk[4] = (f16)p4; pk[5] = (f16)p5; pk[6] = (f16)p6; pk[7] = (f16)p7;
        pa8[g][c] = pk;
      }

    // O += P . V  (x32 MFMAs, full rate; B reads V^T at the lane's own keys)
#pragma unroll
    for (int nt = 0; nt < 4; ++nt) {
      half8 vv[2];
#pragma unroll
      for (int c = 0; c < 2; ++c) {
        const half4 v0 = *(const half4*)(&Vts[nt * 16 + l15][c * 32 + qd * 4]);
        const half4 v1 = *(const half4*)(&Vts[nt * 16 + l15][c * 32 + 16 + qd * 4]);
        vv[c] = __builtin_shufflevector(v0, v1, 0, 1, 2, 3, 4, 5, 6, 7);
      }
#pragma unroll
      for (int g = 0; g < 2; ++g) {
        O[g][nt] = mfma_k32(pa8[g][0], vv[0], O[g][nt]);
        O[g][nt] = mfma_k32(pa8[g][1], vv[1], O[g][nt]);
      }
    }
    __syncthreads();
  }

  // epilogue: reduce lsum over the 4 qd-lane groups (queries live on l15),
  // bounce through LDS to re-index by query=qd*4+r (O's C-layout row), write out
#pragma unroll
  for (int g = 0; g < 2; ++g) {
    float s = lsum[g];
    s += __shfl_xor(s, 16, 64);
    s += __shfl_xor(s, 32, 64);
    if (lane < 16) wsum[w * 32 + g * 16 + lane] = s;
  }
  __syncthreads();
  float inv[2][4];
#pragma unroll
  for (int g = 0; g < 2; ++g)
#pragma unroll
    for (int r = 0; r < 4; ++r)
      inv[g][r] = 1.f / wsum[w * 32 + g * 16 + qd * 4 + r];
#pragma unroll
  for (int g = 0; g < 2; ++g)
#pragma unroll
    for (int r = 0; r < 4; ++r) {
      const int n = qt * 128 + w * 32 + g * 16 + qd * 4 + r;
      f16* dst = Aout + ((long)b * 1024 + n) * 768 + h * 64;
#pragma unroll
      for (int nt = 0; nt < 4; ++nt)
        dst[nt * 16 + l15] = (f16)(O[g][nt][r] * inv[g][r]);
    }
}

// ---------------- proj GEMM + bias -> f32 out ----------------
__global__ __launch_bounds__(256) void proj_kernel(const f16* __restrict__ A, const f16* __restrict__ W,
                                                   const float* __restrict__ bias, float* __restrict__ out) {
  __shared__ __align__(16) f16 As[4096];
  __shared__ __align__(16) f16 Bs[4096];
  f32x4 acc[4][4];
#pragma unroll
  for (int i = 0; i < 4; ++i)
#pragma unroll
    for (int j = 0; j < 4; ++j) acc[i][j] = (f32x4){0.f, 0.f, 0.f, 0.f};
  const long m0 = (long)blockIdx.x * 128;
  const long n0 = (long)blockIdx.y * 128;
  gemm128(A, W, 768, m0, n0, As, Bs, acc);

  const int tid = threadIdx.x, lane = tid & 63, w = tid >> 6;
  const int l15 = lane & 15, qd = lane >> 4;
  const int wr = w >> 1, wc = w & 1;
#pragma unroll
  for (int j = 0; j < 4; ++j) {
    const int col = (int)n0 + 64 * wc + 16 * j + l15;
    const float bv = bias[col];
#pragma unroll
    for (int i = 0; i < 4; ++i) {
      const long m = m0 + 64 * wr + 16 * i + qd * 4;
#pragma unroll
      for (int r = 0; r < 4; ++r)
        out[(m + r) * 768 + col] = acc[i][j][r] + bv;
    }
  }
}

extern "C" void kernel_launch(void* const* d_in, const int* in_sizes, int n_in,
                              void* d_out, int out_size, void* d_ws, size_t ws_size,
                              hipStream_t stream) {
  const float* x_f    = (const float*)d_in[0];
  const float* qkvw_f = (const float*)d_in[1];
  const float* qkvb_f = (const float*)d_in[2];
  const float* projw_f= (const float*)d_in[3];
  const float* projb_f= (const float*)d_in[4];
  // d_in[5], d_in[6]: height/width = 32 (hardcoded)

  char* ws = (char*)d_ws;
  // workspace layout (bytes):
  f16* xh   = (f16*)(ws + 0);           // 16384*768*2  = 25,165,824
  f16* wqh  = (f16*)(ws + 25165824);    // 2304*768*2   =  3,538,944
  f16* wph  = (f16*)(ws + 28704768);    //  768*768*2   =  1,179,648
  f16* Qf   = (f16*)(ws + 29884416);    // 192*1024*64*2 = 25,165,824
  f16* Kf   = (f16*)(ws + 55050240);
  f16* Vf   = (f16*)(ws + 80216064);    // total 105,381,888 B
  f16* Aout = (f16*)(ws + 0);           // aliases xh (dead after qkv_kernel)

  cvt_kernel<<<6144, 256, 0, stream>>>(x_f, xh, 12582912);
  cvt_kernel<<<864, 256, 0, stream>>>(qkvw_f, wqh, 1769472);
  cvt_kernel<<<288, 256, 0, stream>>>(projw_f, wph, 589824);
  qkv_kernel<<<dim3(128, 18), 256, 0, stream>>>(xh, wqh, qkvb_f, Qf, Kf, Vf);
  attn_kernel<<<dim3(8, 192), 256, 0, stream>>>(Qf, Kf, Vf, Aout);
  proj_kernel<<<dim3(128, 6), 256, 0, stream>>>(Aout, wph, projb_f, (float*)d_out);
}